// Round 6
// baseline (408.344 us; speedup 1.0000x reference)
//
#include <hip/hip_runtime.h>
#include <stdint.h>

#define T_LEN 200
#define B_SZ  1024
#define D_DIM 128
#define LOG2E 1.44269504088896340736f

typedef __bf16 bf16_t;
typedef __bf16 bf16x8 __attribute__((ext_vector_type(8)));
typedef float  f32x4  __attribute__((ext_vector_type(4)));

union BF8 { bf16x8 v; bf16_t e[8]; };

__device__ inline float rcp_f(float x) { return __builtin_amdgcn_rcpf(x); }

// Pack two f32 -> bf16x2 dword, RNE (single HW instr).
__device__ inline uint32_t cvt_pk_bf16(float a, float b) {
  uint32_t r;
  asm("v_cvt_pk_bf16_f32 %0, %1, %2" : "=v"(r) : "v"(a), "v"(b));
  return r;
}

// LDS-only barrier: wait LDS ops, leave global loads (vmcnt) in flight.
#define BAR_LDS() asm volatile("s_waitcnt lgkmcnt(0)\n\ts_barrier" ::: "memory")

// ---------------------------------------------------------------------------
// Fused AUGRU scan. Round-6 STRUCTURAL: 32 blocks x 512 thr; each block owns
// TWO independent 16-row batch tiles (rows bb*32.. and bb*32+16..).
// Why: R1/R5 proved scheduling is compiler-owned; R4 proved fewer waves
// exposes the serial chain. The step cost = shared LDS read burst (8 waves
// re-read the block-uniform A-tiles) + one exposed serial chain + barrier.
// Pairing two tiles per barrier period gives every wave TWO independent
// dependence chains (tile B's MFMAs/epilogue fill tile A's stalls), halves
// barrier count per unit work, and keeps 8 waves for latency hiding.
// Weight B-fragments are SHARED between tiles (same 16 cols/wave); only
// per-tile state (as_/acc/gates/sreg/epilogue) duplicates.
// Per-tile math is bit-identical to R3 (same chains, same summation order).
// LDS layouts per tile (halfword index), same as R3:
//   xb: slot(row,k) = (k>>3)*128 + row*8 + (k&7)           (frag = 8*l)
//   sb: slot(row,k) = (k>>3)*128 + (row^(2*((k>>3)&1)))*8 + (k&7)
//       reader frag = 8*(l ^ 2*(lg&1)); writer slots wbase + 8*(i^psi)
// ---------------------------------------------------------------------------
__global__ __launch_bounds__(512, 2) void augru_fused(
    const float* __restrict__ x,
    const float* __restrict__ state,
    const float* __restrict__ att,
    const float* __restrict__ mask,
    const float* __restrict__ Wau, const float* __restrict__ bau,
    const float* __restrict__ Wbu,
    const float* __restrict__ War, const float* __restrict__ bar,
    const float* __restrict__ Wbr,
    const float* __restrict__ Wac, const float* __restrict__ bac,
    const float* __restrict__ Wbc,
    float* __restrict__ out)
{
  __shared__ bf16_t xb[2][2][2048];        // [tile][buf] x tiles (bf16)
  __shared__ bf16_t sb[2][2][2048];        // [tile][buf] state ping-pong
  __shared__ float  am_lds[2][T_LEN * 16]; // [tile] 1/(att*mask), [t][row]

  const int tid = threadIdx.x;
  const int w  = tid >> 6;
  const int l  = tid & 63;
  const int lm = l & 15;
  const int lg = l >> 4;
  const int bb = blockIdx.x;
  const int R0a = bb * 32;
  const int R0b = bb * 32 + 16;
  const int col = w * 16 + lm;

  // --- weight B-fragments (SHARED by both tiles; pre-scaled)
  BF8 xu[4], xr[4], xc[4];   // x-side  (Wau, War, Wac)
  BF8 su[4], sr[4], sc[4];   // state-side (Wbu, Wbr, Wbc)
#pragma unroll
  for (int kk = 0; kk < 4; ++kk) {
#pragma unroll
    for (int j = 0; j < 8; ++j) {
      int k = kk * 32 + lg * 8 + j;
      xu[kk].e[j] = (bf16_t)(Wau[k * 128 + col] * LOG2E);
      xr[kk].e[j] = (bf16_t)(War[k * 128 + col] * LOG2E);
      xc[kk].e[j] = (bf16_t)(Wac[k * 128 + col] * (2.0f * LOG2E));
      su[kk].e[j] = (bf16_t)(Wbu[k * 128 + col] * LOG2E);
      sr[kk].e[j] = (bf16_t)(Wbr[k * 128 + col] * LOG2E);
      sc[kk].e[j] = (bf16_t)(Wbc[k * 128 + col] * (2.0f * LOG2E));
    }
  }
  const float b_u = bau[col] * LOG2E;
  const float b_r = bar[col] * LOG2E;
  const float b_c = bac[col] * (2.0f * LOG2E);
  const f32x4 biasU = {b_u, b_u, b_u, b_u};
  const f32x4 biasR = {b_r, b_r, b_r, b_r};
  const f32x4 biasC = {b_c, b_c, b_c, b_c};
  const f32x4 zero4 = {0.f, 0.f, 0.f, 0.f};

  // --- 1/(att*mask) preload, both tiles
  for (int idx = tid; idx < 2 * T_LEN * 16; idx += 512) {
    int tile = (idx >= T_LEN * 16);
    int j = idx - tile * (T_LEN * 16);
    int t = j >> 4, row = j & 15;
    int Rb = tile ? R0b : R0a;
    am_lds[tile][j] = rcp_f(att[t * B_SZ + Rb + row] * mask[(Rb + row) * T_LEN + t]);
  }

  // --- fp32 state in registers: lane owns (row = lg*4+i, col) per tile
  float sregA[4], sregB[4];
#pragma unroll
  for (int i = 0; i < 4; ++i) {
    sregA[i] = state[(R0a + lg * 4 + i) * 128 + col];
    sregB[i] = state[(R0b + lg * 4 + i) * 128 + col];
  }

  // state bf16 into sb[tile][0], swizzled layout
  for (int idx = tid; idx < 4096; idx += 512) {
    int tile = idx >> 11, j = idx & 2047;
    int row = j >> 7, k = j & 127;
    int Rb = tile ? R0b : R0a;
    sb[tile][0][(k >> 3) * 128 + (row ^ (2 * ((k >> 3) & 1))) * 8 + (k & 7)] =
        (bf16_t)state[(Rb + row) * 128 + k];
  }

  // --- x staging: thread tid stages row=tid&15, float4 chunk sc4=tid>>4
  const int srow = tid & 15;
  const int sc4  = tid >> 4;
  const int stg_pos = (sc4 >> 1) * 128 + srow * 8 + (sc4 & 1) * 4;  // halfwords
  const float* xrowA = x + (size_t)(R0a + srow) * 128 + sc4 * 4;
  const float* xrowB = x + (size_t)(R0b + srow) * 128 + sc4 * 4;
  const size_t xstep = (size_t)B_SZ * 128;
  const size_t xoff_max = (size_t)(T_LEN - 1) * xstep;

  // prologue: stage x(0), x(1) for both tiles; register-prefetch x(2), x(3)
  {
    float4 v;
    uint2 p;
    v = *(const float4*)(xrowA);
    p.x = cvt_pk_bf16(v.x, v.y); p.y = cvt_pk_bf16(v.z, v.w);
    *(uint2*)&xb[0][0][stg_pos] = p;
    v = *(const float4*)(xrowA + xstep);
    p.x = cvt_pk_bf16(v.x, v.y); p.y = cvt_pk_bf16(v.z, v.w);
    *(uint2*)&xb[0][1][stg_pos] = p;
    v = *(const float4*)(xrowB);
    p.x = cvt_pk_bf16(v.x, v.y); p.y = cvt_pk_bf16(v.z, v.w);
    *(uint2*)&xb[1][0][stg_pos] = p;
    v = *(const float4*)(xrowB + xstep);
    p.x = cvt_pk_bf16(v.x, v.y); p.y = cvt_pk_bf16(v.z, v.w);
    *(uint2*)&xb[1][1][stg_pos] = p;
  }
  float4 xqEa = *(const float4*)(xrowA + 2 * xstep);   // x(t+2), even t, tile A
  float4 xqEb = *(const float4*)(xrowB + 2 * xstep);   // tile B
  float4 xqOa = *(const float4*)(xrowA + 3 * xstep);   // x(t+2), odd t
  float4 xqOb = *(const float4*)(xrowB + 3 * xstep);
  size_t offE = 4 * xstep;   // next reload for even-parity buffers
  size_t offO = 5 * xstep;   // next reload for odd-parity buffers

  __syncthreads();   // full drain once

  // x-gates(0) for both tiles from xb[.][0]
  f32x4 gUa, gRa, gCa, gUb, gRb, gCb;
  {
    bf16x8 axA[4], axB[4];
#pragma unroll
    for (int kk = 0; kk < 4; ++kk) {
      axA[kk] = *(const bf16x8*)&xb[0][0][kk * 512 + 8 * l];
      axB[kk] = *(const bf16x8*)&xb[1][0][kk * 512 + 8 * l];
    }
    gUa = __builtin_amdgcn_mfma_f32_16x16x32_bf16(axA[0], xu[0].v, biasU, 0, 0, 0);
    gRa = __builtin_amdgcn_mfma_f32_16x16x32_bf16(axA[0], xr[0].v, biasR, 0, 0, 0);
    gCa = __builtin_amdgcn_mfma_f32_16x16x32_bf16(axA[0], xc[0].v, biasC, 0, 0, 0);
    gUb = __builtin_amdgcn_mfma_f32_16x16x32_bf16(axB[0], xu[0].v, biasU, 0, 0, 0);
    gRb = __builtin_amdgcn_mfma_f32_16x16x32_bf16(axB[0], xr[0].v, biasR, 0, 0, 0);
    gCb = __builtin_amdgcn_mfma_f32_16x16x32_bf16(axB[0], xc[0].v, biasC, 0, 0, 0);
#pragma unroll
    for (int kk = 1; kk < 4; ++kk) {
      gUa = __builtin_amdgcn_mfma_f32_16x16x32_bf16(axA[kk], xu[kk].v, gUa, 0, 0, 0);
      gRa = __builtin_amdgcn_mfma_f32_16x16x32_bf16(axA[kk], xr[kk].v, gRa, 0, 0, 0);
      gCa = __builtin_amdgcn_mfma_f32_16x16x32_bf16(axA[kk], xc[kk].v, gCa, 0, 0, 0);
      gUb = __builtin_amdgcn_mfma_f32_16x16x32_bf16(axB[kk], xu[kk].v, gUb, 0, 0, 0);
      gRb = __builtin_amdgcn_mfma_f32_16x16x32_bf16(axB[kk], xr[kk].v, gRb, 0, 0, 0);
      gCb = __builtin_amdgcn_mfma_f32_16x16x32_bf16(axB[kk], xc[kk].v, gCb, 0, 0, 0);
    }
  }

  const int lx8   = 8 * (l ^ (2 * (lg & 1)));        // swizzled sb frag offset
  const int psi   = 2 * ((col >> 3) & 1);            // writer value permutation
  const int wbase = (col >> 3) * 128 + lg * 32 + (col & 7);
  int am_off = lg * 4;                                // walking am index

  BAR_LDS();   // protect xb[.][0] before step 0 overwrites them

  // One paired scan step: advances BOTH tiles from t to t+1.
  auto step = [&](int t, float4& xqa, float4& xqb, size_t& xoff) {
    const int rp = t & 1;

    // s-frag reads, both tiles
    bf16x8 asA[4], asB[4];
#pragma unroll
    for (int kk = 0; kk < 4; ++kk) {
      asA[kk] = *(const bf16x8*)&sb[0][rp][kk * 512 + lx8];
      asB[kk] = *(const bf16x8*)&sb[1][rp][kk * 512 + lx8];
    }
    // am reads (part of the read burst; consumed in epilogue)
    union F4 { float4 v; float e[4]; } amA, amB;
    amA.v = *(const float4*)&am_lds[0][am_off];
    amB.v = *(const float4*)&am_lds[1][am_off];
    am_off += 16;

    // stage x(t+2) into xb[.][rp]; reload prefetch regs with x(t+4)
    {
      uint2 p;
      p.x = cvt_pk_bf16(xqa.x, xqa.y); p.y = cvt_pk_bf16(xqa.z, xqa.w);
      *(uint2*)&xb[0][rp][stg_pos] = p;
      p.x = cvt_pk_bf16(xqb.x, xqb.y); p.y = cvt_pk_bf16(xqb.z, xqb.w);
      *(uint2*)&xb[1][rp][stg_pos] = p;
    }
    xqa = *(const float4*)(xrowA + xoff);
    xqb = *(const float4*)(xrowB + xoff);
    xoff += 2 * xstep; if (xoff > xoff_max) xoff = xoff_max;

    // state-side MFMAs, A/B chains interleaved (2x ILP on the matrix pipe);
    // per-chain summation order identical to R3 -> bit-identical numerics
    f32x4 aRa = __builtin_amdgcn_mfma_f32_16x16x32_bf16(asA[0], sr[0].v, gRa, 0, 0, 0);
    f32x4 aRb = __builtin_amdgcn_mfma_f32_16x16x32_bf16(asB[0], sr[0].v, gRb, 0, 0, 0);
    f32x4 bCa = __builtin_amdgcn_mfma_f32_16x16x32_bf16(asA[0], sc[0].v, zero4, 0, 0, 0);
    f32x4 bCb = __builtin_amdgcn_mfma_f32_16x16x32_bf16(asB[0], sc[0].v, zero4, 0, 0, 0);
    f32x4 aUa = __builtin_amdgcn_mfma_f32_16x16x32_bf16(asA[0], su[0].v, gUa, 0, 0, 0);
    f32x4 aUb = __builtin_amdgcn_mfma_f32_16x16x32_bf16(asB[0], su[0].v, gUb, 0, 0, 0);
#pragma unroll
    for (int kk = 1; kk < 4; ++kk) {
      aRa = __builtin_amdgcn_mfma_f32_16x16x32_bf16(asA[kk], sr[kk].v, aRa, 0, 0, 0);
      aRb = __builtin_amdgcn_mfma_f32_16x16x32_bf16(asB[kk], sr[kk].v, aRb, 0, 0, 0);
      bCa = __builtin_amdgcn_mfma_f32_16x16x32_bf16(asA[kk], sc[kk].v, bCa, 0, 0, 0);
      bCb = __builtin_amdgcn_mfma_f32_16x16x32_bf16(asB[kk], sc[kk].v, bCb, 0, 0, 0);
      aUa = __builtin_amdgcn_mfma_f32_16x16x32_bf16(asA[kk], su[kk].v, aUa, 0, 0, 0);
      aUb = __builtin_amdgcn_mfma_f32_16x16x32_bf16(asB[kk], su[kk].v, aUb, 0, 0, 0);
    }

    // x-frag reads + x-side gates for t+1, both tiles
    bf16x8 axA[4], axB[4];
#pragma unroll
    for (int kk = 0; kk < 4; ++kk) {
      axA[kk] = *(const bf16x8*)&xb[0][rp ^ 1][kk * 512 + 8 * l];
      axB[kk] = *(const bf16x8*)&xb[1][rp ^ 1][kk * 512 + 8 * l];
    }
    f32x4 nUa = __builtin_amdgcn_mfma_f32_16x16x32_bf16(axA[0], xu[0].v, biasU, 0, 0, 0);
    f32x4 nUb = __builtin_amdgcn_mfma_f32_16x16x32_bf16(axB[0], xu[0].v, biasU, 0, 0, 0);
    f32x4 nRa = __builtin_amdgcn_mfma_f32_16x16x32_bf16(axA[0], xr[0].v, biasR, 0, 0, 0);
    f32x4 nRb = __builtin_amdgcn_mfma_f32_16x16x32_bf16(axB[0], xr[0].v, biasR, 0, 0, 0);
    f32x4 nCa = __builtin_amdgcn_mfma_f32_16x16x32_bf16(axA[0], xc[0].v, biasC, 0, 0, 0);
    f32x4 nCb = __builtin_amdgcn_mfma_f32_16x16x32_bf16(axB[0], xc[0].v, biasC, 0, 0, 0);
#pragma unroll
    for (int kk = 1; kk < 4; ++kk) {
      nUa = __builtin_amdgcn_mfma_f32_16x16x32_bf16(axA[kk], xu[kk].v, nUa, 0, 0, 0);
      nUb = __builtin_amdgcn_mfma_f32_16x16x32_bf16(axB[kk], xu[kk].v, nUb, 0, 0, 0);
      nRa = __builtin_amdgcn_mfma_f32_16x16x32_bf16(axA[kk], xr[kk].v, nRa, 0, 0, 0);
      nRb = __builtin_amdgcn_mfma_f32_16x16x32_bf16(axB[kk], xr[kk].v, nRb, 0, 0, 0);
      nCa = __builtin_amdgcn_mfma_f32_16x16x32_bf16(axA[kk], xc[kk].v, nCa, 0, 0, 0);
      nCb = __builtin_amdgcn_mfma_f32_16x16x32_bf16(axB[kk], xc[kk].v, nCb, 0, 0, 0);
    }

    // epilogues (two independent chains per i; compiler interleaves)
    bf16_t* wbA = sb[0][rp ^ 1];
    bf16_t* wbB = sb[1][rp ^ 1];
#pragma unroll
    for (int i = 0; i < 4; ++i) {
      float XuA = __builtin_amdgcn_exp2f(-aUa[i]);
      float kA  = rcp_f(fmaf(XuA, amA.e[i], amA.e[i]));
      float rA  = rcp_f(1.0f + __builtin_amdgcn_exp2f(-aRa[i]));
      float wcA = fmaf(rA, bCa[i], gCa[i]);
      float cgA = fmaf(-2.0f, rcp_f(__builtin_amdgcn_exp2f(wcA) + 1.0f), 1.0f);
      float sfA = fmaf(kA, cgA - sregA[i], sregA[i]);
      sregA[i] = sfA;
      wbA[wbase + 8 * (i ^ psi)] = (bf16_t)sfA;

      float XuB = __builtin_amdgcn_exp2f(-aUb[i]);
      float kB  = rcp_f(fmaf(XuB, amB.e[i], amB.e[i]));
      float rB  = rcp_f(1.0f + __builtin_amdgcn_exp2f(-aRb[i]));
      float wcB = fmaf(rB, bCb[i], gCb[i]);
      float cgB = fmaf(-2.0f, rcp_f(__builtin_amdgcn_exp2f(wcB) + 1.0f), 1.0f);
      float sfB = fmaf(kB, cgB - sregB[i], sregB[i]);
      sregB[i] = sfB;
      wbB[wbase + 8 * (i ^ psi)] = (bf16_t)sfB;
    }

    // rotate pipelined gate registers
    gUa = nUa; gRa = nRa; gCa = nCa;
    gUb = nUb; gRb = nRb; gCb = nCb;

    BAR_LDS();
  };

#pragma unroll 1
  for (int t = 0; t < T_LEN; t += 2) {
    step(t,     xqEa, xqEb, offE);
    step(t + 1, xqOa, xqOb, offO);
  }

#pragma unroll
  for (int i = 0; i < 4; ++i) {
    out[(R0a + lg * 4 + i) * 128 + col] = sregA[i];
    out[(R0b + lg * 4 + i) * 128 + col] = sregB[i];
  }
}

// ---------------------------------------------------------------------------
extern "C" void kernel_launch(void* const* d_in, const int* in_sizes, int n_in,
                              void* d_out, int out_size, void* d_ws, size_t ws_size,
                              hipStream_t stream)
{
  const float* x    = (const float*)d_in[0];
  const float* st   = (const float*)d_in[1];
  const float* att  = (const float*)d_in[2];
  const float* mask = (const float*)d_in[3];
  // d_in[4] = max_len (unused; shapes hard-coded)
  const float* Wau  = (const float*)d_in[5];
  const float* bau  = (const float*)d_in[6];
  const float* Wbu  = (const float*)d_in[7];
  const float* War  = (const float*)d_in[8];
  const float* bar  = (const float*)d_in[9];
  const float* Wbr  = (const float*)d_in[10];
  const float* Wac  = (const float*)d_in[11];
  const float* bac  = (const float*)d_in[12];
  const float* Wbc  = (const float*)d_in[13];

  (void)d_ws; (void)ws_size;

  augru_fused<<<dim3(32), dim3(512), 0, stream>>>(
      x, st, att, mask, Wau, bau, Wbu, War, bar, Wbr, Wac, bac, Wbc,
      (float*)d_out);
}